// Round 1
// baseline (18544.531 us; speedup 1.0000x reference)
//
#include <hip/hip_runtime.h>
#include <stdint.h>

#define NSTEP 64
#define BATCH 32
#define EMBED_D 1536
#define ACT_D 16
#define DETER 2048
#define STOCH 512
#define HIDDEN 1024
#define FEAT 2560   // DETER + STOCH

__device__ __forceinline__ float eluf(float x) { return x > 0.f ? x : expf(x) - 1.f; }
__device__ __forceinline__ float sigf(float x) { return 1.f / (1.f + expf(-x)); }

// ---------------- generic tiled f32 GEMM: C[r][j] = bias[j] + sum_k A[r][k]*W[j][k]
// grid: (J/64, R/64), block 256. K multiple of 16.
__global__ __launch_bounds__(256) void gemm_bt_bias(
    const float* __restrict__ A, int lda,
    const float* __restrict__ W, int ldw,
    const float* __restrict__ bias,
    float* __restrict__ C, int ldc, int K)
{
    __shared__ float As[16][68];
    __shared__ float Ws[16][68];
    int tid = threadIdx.x;
    int tx = tid & 15, ty = tid >> 4;
    int rbase = blockIdx.y * 64, jbase = blockIdx.x * 64;
    float acc[4][4];
#pragma unroll
    for (int i = 0; i < 4; i++)
#pragma unroll
        for (int j = 0; j < 4; j++) acc[i][j] = 0.f;
    int lr = tid >> 2;
    int lk = (tid & 3) << 2;
    for (int kt = 0; kt < K; kt += 16) {
        float4 av = *reinterpret_cast<const float4*>(&A[(size_t)(rbase + lr) * lda + kt + lk]);
        float4 wv = *reinterpret_cast<const float4*>(&W[(size_t)(jbase + lr) * ldw + kt + lk]);
        As[lk + 0][lr] = av.x; As[lk + 1][lr] = av.y; As[lk + 2][lr] = av.z; As[lk + 3][lr] = av.w;
        Ws[lk + 0][lr] = wv.x; Ws[lk + 1][lr] = wv.y; Ws[lk + 2][lr] = wv.z; Ws[lk + 3][lr] = wv.w;
        __syncthreads();
#pragma unroll
        for (int kk = 0; kk < 16; kk++) {
            float a0 = As[kk][ty * 4 + 0], a1 = As[kk][ty * 4 + 1];
            float a2 = As[kk][ty * 4 + 2], a3 = As[kk][ty * 4 + 3];
            float w0 = Ws[kk][tx * 4 + 0], w1 = Ws[kk][tx * 4 + 1];
            float w2 = Ws[kk][tx * 4 + 2], w3 = Ws[kk][tx * 4 + 3];
            acc[0][0] += a0 * w0; acc[0][1] += a0 * w1; acc[0][2] += a0 * w2; acc[0][3] += a0 * w3;
            acc[1][0] += a1 * w0; acc[1][1] += a1 * w1; acc[1][2] += a1 * w2; acc[1][3] += a1 * w3;
            acc[2][0] += a2 * w0; acc[2][1] += a2 * w1; acc[2][2] += a2 * w2; acc[2][3] += a2 * w3;
            acc[3][0] += a3 * w0; acc[3][1] += a3 * w1; acc[3][2] += a3 * w2; acc[3][3] += a3 * w3;
        }
        __syncthreads();
    }
#pragma unroll
    for (int i = 0; i < 4; i++) {
        int r = rbase + ty * 4 + i;
#pragma unroll
        for (int j = 0; j < 4; j++) {
            int c = jbase + tx * 4 + j;
            C[(size_t)r * ldc + c] = acc[i][j] + bias[c];
        }
    }
}

// ---------------- x1 = preA[t] + m * (z @ W_z^T) ; out 32x1024, K=512
// grid 128, block (32,8)
__global__ __launch_bounds__(256) void k_x1(
    const float* __restrict__ preA_t, const float* __restrict__ z,
    const uint8_t* __restrict__ reset_t,
    const float* __restrict__ Wz, float* __restrict__ x1)
{
    int b = threadIdx.x;
    int j = blockIdx.x * 8 + threadIdx.y;
    const float* zr = z + (size_t)b * STOCH;
    const float* wr = Wz + (size_t)j * STOCH;
    float acc = 0.f;
    for (int k = 0; k < STOCH; k += 4) {
        float4 zv = *reinterpret_cast<const float4*>(zr + k);
        float4 wv = *reinterpret_cast<const float4*>(wr + k);
        acc += zv.x * wv.x + zv.y * wv.y + zv.z * wv.z + zv.w * wv.w;
    }
    float m = reset_t[b] ? 0.f : 1.f;
    x1[b * HIDDEN + j] = preA_t[b * HIDDEN + j] + m * acc;
}

#define ZLD 1028  // padded LDS row stride (floats), 16B-aligned, breaks bank aliasing

// ---------------- GRU: in-block LN+elu of x1 -> za (LDS); gi,gh dots; gates; h_new
// grid 256, block (32,8)
__global__ __launch_bounds__(256) void k_gru(
    const float* __restrict__ x1,
    const float* __restrict__ ln_g, const float* __restrict__ ln_b,
    const float* __restrict__ Wih, const float* __restrict__ Whh,
    const float* __restrict__ bih, const float* __restrict__ bhh,
    const float* __restrict__ hprev, int hstride,
    const uint8_t* __restrict__ reset_t,
    float* __restrict__ hout /* stride FEAT */)
{
    __shared__ float za[BATCH * ZLD];
    __shared__ float red_s[BATCH][8];
    __shared__ float red_q[BATCH][8];
    __shared__ float mv[BATCH][2];
    int b = threadIdx.x, y = threadIdx.y;
    int k0 = y * 128;
    float s = 0.f, q = 0.f;
    for (int k = 0; k < 128; k += 4) {
        float4 v = *reinterpret_cast<const float4*>(&x1[b * HIDDEN + k0 + k]);
        *reinterpret_cast<float4*>(&za[b * ZLD + k0 + k]) = v;
        s += v.x + v.y + v.z + v.w;
        q += v.x * v.x + v.y * v.y + v.z * v.z + v.w * v.w;
    }
    red_s[b][y] = s; red_q[b][y] = q;
    __syncthreads();
    if (y == 0) {
        float ss = 0.f, qq = 0.f;
        for (int i = 0; i < 8; i++) { ss += red_s[b][i]; qq += red_q[b][i]; }
        float mean = ss / HIDDEN;
        float var = qq / HIDDEN - mean * mean;
        mv[b][0] = mean; mv[b][1] = rsqrtf(var + 1e-5f);
    }
    __syncthreads();
    {
        float mean = mv[b][0], rstd = mv[b][1];
        for (int k = 0; k < 128; k++) {
            int kk = k0 + k;
            float xv = za[b * ZLD + kk];
            za[b * ZLD + kk] = eluf((xv - mean) * rstd * ln_g[kk] + ln_b[kk]);
        }
    }
    __syncthreads();

    int j = blockIdx.x * 8 + y;
    float gi_r = bih[j], gi_u = bih[j + DETER], gi_n = bih[j + 2 * DETER];
    {
        const float* wr = Wih + (size_t)j * HIDDEN;
        const float* wu = wr + (size_t)DETER * HIDDEN;
        const float* wn = wu + (size_t)DETER * HIDDEN;
        for (int k = 0; k < HIDDEN; k += 4) {
            float4 zv = *reinterpret_cast<const float4*>(&za[b * ZLD + k]);
            float4 a = *reinterpret_cast<const float4*>(wr + k);
            float4 c = *reinterpret_cast<const float4*>(wu + k);
            float4 d = *reinterpret_cast<const float4*>(wn + k);
            gi_r += zv.x * a.x + zv.y * a.y + zv.z * a.z + zv.w * a.w;
            gi_u += zv.x * c.x + zv.y * c.y + zv.z * c.z + zv.w * c.w;
            gi_n += zv.x * d.x + zv.y * d.y + zv.z * d.z + zv.w * d.w;
        }
    }
    float hr_ = 0.f, hu_ = 0.f, hn_ = 0.f;
    const float* hp = hprev + (size_t)b * hstride;
    {
        const float* vr = Whh + (size_t)j * DETER;
        const float* vu = vr + (size_t)DETER * DETER;
        const float* vn = vu + (size_t)DETER * DETER;
        for (int k = 0; k < DETER; k += 4) {
            float4 hv = *reinterpret_cast<const float4*>(hp + k);
            float4 a = *reinterpret_cast<const float4*>(vr + k);
            float4 c = *reinterpret_cast<const float4*>(vu + k);
            float4 d = *reinterpret_cast<const float4*>(vn + k);
            hr_ += hv.x * a.x + hv.y * a.y + hv.z * a.z + hv.w * a.w;
            hu_ += hv.x * c.x + hv.y * c.y + hv.z * c.z + hv.w * c.w;
            hn_ += hv.x * d.x + hv.y * d.y + hv.z * d.z + hv.w * d.w;
        }
    }
    float m = reset_t[b] ? 0.f : 1.f;
    float gh_r = bhh[j] + m * hr_;
    float gh_u = bhh[j + DETER] + m * hu_;
    float gh_n = bhh[j + 2 * DETER] + m * hn_;
    float r = sigf(gi_r + gh_r);
    float u = sigf(gi_u + gh_u);
    float cand = tanhf(gi_n + r * gh_n);
    float hm = m * hp[j];
    hout[(size_t)b * FEAT + j] = (1.f - u) * cand + u * hm;
}

// ---------------- x2 = preE[t] + h_new @ W_ph^T ; out 32x1024, K=2048
__global__ __launch_bounds__(256) void k_x2(
    const float* __restrict__ preE_t, const float* __restrict__ h /*stride FEAT*/,
    const float* __restrict__ Wph, float* __restrict__ x2)
{
    int b = threadIdx.x;
    int j = blockIdx.x * 8 + threadIdx.y;
    const float* hr = h + (size_t)b * FEAT;
    const float* wr = Wph + (size_t)j * DETER;
    float acc = 0.f;
    for (int k = 0; k < DETER; k += 4) {
        float4 hv = *reinterpret_cast<const float4*>(hr + k);
        float4 wv = *reinterpret_cast<const float4*>(wr + k);
        acc += hv.x * wv.x + hv.y * wv.y + hv.z * wv.z + hv.w * wv.w;
    }
    x2[b * HIDDEN + j] = preE_t[b * HIDDEN + j] + acc;
}

// ---------------- post: in-block LN+elu of x2 -> pin (LDS); post GEMM; sample
// grid 64, block (32,8); j in [0,512)
__global__ __launch_bounds__(256) void k_post(
    const float* __restrict__ x2,
    const float* __restrict__ ln_g, const float* __restrict__ ln_b,
    const float* __restrict__ Wpost, const float* __restrict__ bpost,
    const float* __restrict__ noise_t,
    float* __restrict__ posts_t,
    float* __restrict__ samples_t,
    float* __restrict__ feat_t)
{
    __shared__ float pin[BATCH * ZLD];
    __shared__ float red_s[BATCH][8];
    __shared__ float red_q[BATCH][8];
    __shared__ float mv[BATCH][2];
    int b = threadIdx.x, y = threadIdx.y;
    int k0 = y * 128;
    float s = 0.f, q = 0.f;
    for (int k = 0; k < 128; k += 4) {
        float4 v = *reinterpret_cast<const float4*>(&x2[b * HIDDEN + k0 + k]);
        *reinterpret_cast<float4*>(&pin[b * ZLD + k0 + k]) = v;
        s += v.x + v.y + v.z + v.w;
        q += v.x * v.x + v.y * v.y + v.z * v.z + v.w * v.w;
    }
    red_s[b][y] = s; red_q[b][y] = q;
    __syncthreads();
    if (y == 0) {
        float ss = 0.f, qq = 0.f;
        for (int i = 0; i < 8; i++) { ss += red_s[b][i]; qq += red_q[b][i]; }
        float mean = ss / HIDDEN;
        float var = qq / HIDDEN - mean * mean;
        mv[b][0] = mean; mv[b][1] = rsqrtf(var + 1e-5f);
    }
    __syncthreads();
    {
        float mean = mv[b][0], rstd = mv[b][1];
        for (int k = 0; k < 128; k++) {
            int kk = k0 + k;
            float xv = pin[b * ZLD + kk];
            pin[b * ZLD + kk] = eluf((xv - mean) * rstd * ln_g[kk] + ln_b[kk]);
        }
    }
    __syncthreads();

    int j = blockIdx.x * 8 + y;  // 0..511
    float pm = bpost[j], ps = bpost[j + STOCH];
    const float* wm = Wpost + (size_t)j * HIDDEN;
    const float* wsp = Wpost + (size_t)(j + STOCH) * HIDDEN;
    for (int k = 0; k < HIDDEN; k += 4) {
        float4 pv = *reinterpret_cast<const float4*>(&pin[b * ZLD + k]);
        float4 a = *reinterpret_cast<const float4*>(wm + k);
        float4 c = *reinterpret_cast<const float4*>(wsp + k);
        pm += pv.x * a.x + pv.y * a.y + pv.z * a.z + pv.w * a.w;
        ps += pv.x * c.x + pv.y * c.y + pv.z * c.z + pv.w * c.w;
    }
    posts_t[(size_t)b * HIDDEN + j] = pm;
    posts_t[(size_t)b * HIDDEN + STOCH + j] = ps;
    float sp = fmaxf(ps, 0.f) + log1pf(expf(-fabsf(ps)));
    float stdv = sp + 0.1f;
    float smp = pm + stdv * noise_t[(size_t)b * STOCH + j];
    samples_t[(size_t)b * STOCH + j] = smp;
    feat_t[(size_t)b * FEAT + DETER + j] = smp;
}

// ---------------- row LN+elu in place (prior path), grid R blocks, 256 threads
__global__ __launch_bounds__(256) void ln_elu_rows(
    float* __restrict__ X, const float* __restrict__ g, const float* __restrict__ bb)
{
    __shared__ float sbuf[256];
    __shared__ float qbuf[256];
    int r = blockIdx.x, t = threadIdx.x;
    float* row = X + (size_t)r * HIDDEN;
    float v[4];
    float s = 0.f, q = 0.f;
#pragma unroll
    for (int i = 0; i < 4; i++) {
        v[i] = row[t + i * 256];
        s += v[i]; q += v[i] * v[i];
    }
    sbuf[t] = s; qbuf[t] = q;
    __syncthreads();
    for (int off = 128; off > 0; off >>= 1) {
        if (t < off) { sbuf[t] += sbuf[t + off]; qbuf[t] += qbuf[t + off]; }
        __syncthreads();
    }
    float mean = sbuf[0] / HIDDEN;
    float var = qbuf[0] / HIDDEN - mean * mean;
    float rstd = rsqrtf(var + 1e-5f);
#pragma unroll
    for (int i = 0; i < 4; i++) {
        int c = t + i * 256;
        row[c] = eluf((v[i] - mean) * rstd * g[c] + bb[c]);
    }
}

__global__ __launch_bounds__(256) void k_copy_last(
    const float* __restrict__ feat63, const float* __restrict__ samp63,
    float* __restrict__ hlast, float* __restrict__ zlast)
{
    int i = blockIdx.x * 256 + threadIdx.x;
    if (i < BATCH * DETER) {
        int b = i / DETER, k = i % DETER;
        hlast[i] = feat63[(size_t)b * FEAT + k];
    }
    if (i < BATCH * STOCH) {
        zlast[i] = samp63[i];
    }
}

extern "C" void kernel_launch(void* const* d_in, const int* in_sizes, int n_in,
                              void* d_out, int out_size, void* d_ws, size_t ws_size,
                              hipStream_t stream)
{
    (void)in_sizes; (void)n_in; (void)out_size; (void)ws_size;
    const float*   embed  = (const float*)d_in[0];
    const float*   action = (const float*)d_in[1];
    const uint8_t* reset  = (const uint8_t*)d_in[2];
    const float*   h0     = (const float*)d_in[3];
    const float*   z0     = (const float*)d_in[4];
    const float*   noises = (const float*)d_in[5];
    const float*   W_z    = (const float*)d_in[6];
    const float*   b_z    = (const float*)d_in[7];
    const float*   W_a    = (const float*)d_in[8];
    const float*   ln_in_g = (const float*)d_in[9];
    const float*   ln_in_b = (const float*)d_in[10];
    const float*   Wih    = (const float*)d_in[11];
    const float*   Whh    = (const float*)d_in[12];
    const float*   bih    = (const float*)d_in[13];
    const float*   bhh    = (const float*)d_in[14];
    const float*   W_ph   = (const float*)d_in[15];
    const float*   b_ph   = (const float*)d_in[16];
    const float*   W_pe   = (const float*)d_in[17];
    const float*   ln_post_g = (const float*)d_in[18];
    const float*   ln_post_b = (const float*)d_in[19];
    const float*   W_post = (const float*)d_in[20];
    const float*   b_post = (const float*)d_in[21];
    const float*   W_prh  = (const float*)d_in[22];
    const float*   b_prh  = (const float*)d_in[23];
    const float*   ln_pr_g = (const float*)d_in[24];
    const float*   ln_pr_b = (const float*)d_in[25];
    const float*   W_pr   = (const float*)d_in[26];
    const float*   b_pr   = (const float*)d_in[27];

    float* out     = (float*)d_out;
    float* priors  = out;                  // 64*32*1024
    float* posts   = out + 2097152;        // 64*32*1024
    float* samples = out + 4194304;        // 64*32*512
    float* feats   = out + 5242880;        // 64*32*2560
    float* hlast   = out + 10485760;       // 32*2048
    float* zlast   = out + 10551296;       // 32*512

    float* ws   = (float*)d_ws;
    float* preA = ws;                // 2097152 floats
    float* preE = ws + 2097152;      // 2097152 floats
    float* x1   = ws + 4194304;      // 32768
    float* x2   = ws + 4227072;      // 32768
    float* prx  = preA;              // alias: preA dead after the scan

    dim3 blk256(256);
    dim3 b32x8(32, 8);
    const int RB = (NSTEP * BATCH) / 64;   // 32 row-blocks of 64

    // precompute: preA = b_z + action @ W_a^T ; preE = b_ph + embed @ W_pe^T
    gemm_bt_bias<<<dim3(HIDDEN / 64, RB), blk256, 0, stream>>>(action, ACT_D, W_a, ACT_D, b_z, preA, HIDDEN, ACT_D);
    gemm_bt_bias<<<dim3(HIDDEN / 64, RB), blk256, 0, stream>>>(embed, EMBED_D, W_pe, EMBED_D, b_ph, preE, HIDDEN, EMBED_D);

    for (int t = 0; t < NSTEP; ++t) {
        const float* z = (t == 0) ? z0 : (samples + (size_t)(t - 1) * BATCH * STOCH);
        const float* h = (t == 0) ? h0 : (feats + (size_t)(t - 1) * BATCH * FEAT);
        int hstride = (t == 0) ? DETER : FEAT;
        const uint8_t* rs = reset + (size_t)t * BATCH;
        float* h_t = feats + (size_t)t * BATCH * FEAT;

        k_x1<<<dim3(HIDDEN / 8), b32x8, 0, stream>>>(preA + (size_t)t * BATCH * HIDDEN, z, rs, W_z, x1);
        k_gru<<<dim3(DETER / 8), b32x8, 0, stream>>>(x1, ln_in_g, ln_in_b, Wih, Whh, bih, bhh, h, hstride, rs, h_t);
        k_x2<<<dim3(HIDDEN / 8), b32x8, 0, stream>>>(preE + (size_t)t * BATCH * HIDDEN, h_t, W_ph, x2);
        k_post<<<dim3(STOCH / 8), b32x8, 0, stream>>>(x2, ln_post_g, ln_post_b, W_post, b_post,
            noises + (size_t)t * BATCH * STOCH,
            posts + (size_t)t * BATCH * HIDDEN,
            samples + (size_t)t * BATCH * STOCH,
            h_t);
    }

    // prior over all states_h (rows of feats, first DETER cols)
    gemm_bt_bias<<<dim3(HIDDEN / 64, RB), blk256, 0, stream>>>(feats, FEAT, W_prh, DETER, b_prh, prx, HIDDEN, DETER);
    ln_elu_rows<<<dim3(NSTEP * BATCH), blk256, 0, stream>>>(prx, ln_pr_g, ln_pr_b);
    gemm_bt_bias<<<dim3(HIDDEN / 64, RB), blk256, 0, stream>>>(prx, HIDDEN, W_pr, HIDDEN, b_pr, priors, HIDDEN, HIDDEN);

    k_copy_last<<<dim3(256), blk256, 0, stream>>>(
        feats + (size_t)(NSTEP - 1) * BATCH * FEAT,
        samples + (size_t)(NSTEP - 1) * BATCH * STOCH,
        hlast, zlast);
}

// Round 2
// 14612.750 us; speedup vs baseline: 1.2691x; 1.2691x over previous
//
#include <hip/hip_runtime.h>
#include <stdint.h>

#define NSTEP 64
#define BATCH 32
#define EMBED_D 1536
#define ACT_D 16
#define DETER 2048
#define STOCH 512
#define HIDDEN 1024
#define FEAT 2560   // DETER + STOCH

__device__ __forceinline__ float eluf(float x) { return x > 0.f ? x : expf(x) - 1.f; }
__device__ __forceinline__ float sigf(float x) { return 1.f / (1.f + expf(-x)); }

// ---------------- generic tiled f32 GEMM: C[r][j] = bias[j] + sum_k A[r][k]*W[j][k]
// grid: (J/64, R/64), block 256. K multiple of 16.
__global__ __launch_bounds__(256) void gemm_bt_bias(
    const float* __restrict__ A, int lda,
    const float* __restrict__ W, int ldw,
    const float* __restrict__ bias,
    float* __restrict__ C, int ldc, int K)
{
    __shared__ float As[16][68];
    __shared__ float Ws[16][68];
    int tid = threadIdx.x;
    int tx = tid & 15, ty = tid >> 4;
    int rbase = blockIdx.y * 64, jbase = blockIdx.x * 64;
    float acc[4][4];
#pragma unroll
    for (int i = 0; i < 4; i++)
#pragma unroll
        for (int j = 0; j < 4; j++) acc[i][j] = 0.f;
    int lr = tid >> 2;
    int lk = (tid & 3) << 2;
    for (int kt = 0; kt < K; kt += 16) {
        float4 av = *reinterpret_cast<const float4*>(&A[(size_t)(rbase + lr) * lda + kt + lk]);
        float4 wv = *reinterpret_cast<const float4*>(&W[(size_t)(jbase + lr) * ldw + kt + lk]);
        As[lk + 0][lr] = av.x; As[lk + 1][lr] = av.y; As[lk + 2][lr] = av.z; As[lk + 3][lr] = av.w;
        Ws[lk + 0][lr] = wv.x; Ws[lk + 1][lr] = wv.y; Ws[lk + 2][lr] = wv.z; Ws[lk + 3][lr] = wv.w;
        __syncthreads();
#pragma unroll
        for (int kk = 0; kk < 16; kk++) {
            float a0 = As[kk][ty * 4 + 0], a1 = As[kk][ty * 4 + 1];
            float a2 = As[kk][ty * 4 + 2], a3 = As[kk][ty * 4 + 3];
            float w0 = Ws[kk][tx * 4 + 0], w1 = Ws[kk][tx * 4 + 1];
            float w2 = Ws[kk][tx * 4 + 2], w3 = Ws[kk][tx * 4 + 3];
            acc[0][0] += a0 * w0; acc[0][1] += a0 * w1; acc[0][2] += a0 * w2; acc[0][3] += a0 * w3;
            acc[1][0] += a1 * w0; acc[1][1] += a1 * w1; acc[1][2] += a1 * w2; acc[1][3] += a1 * w3;
            acc[2][0] += a2 * w0; acc[2][1] += a2 * w1; acc[2][2] += a2 * w2; acc[2][3] += a2 * w3;
            acc[3][0] += a3 * w0; acc[3][1] += a3 * w1; acc[3][2] += a3 * w2; acc[3][3] += a3 * w3;
        }
        __syncthreads();
    }
#pragma unroll
    for (int i = 0; i < 4; i++) {
        int r = rbase + ty * 4 + i;
#pragma unroll
        for (int j = 0; j < 4; j++) {
            int c = jbase + tx * 4 + j;
            C[(size_t)r * ldc + c] = acc[i][j] + bias[c];
        }
    }
}

// ---------------- x1[b][j] = preA_t[b][j] + m_b * sum_k z[b][k] Wz[j][k]
// grid 1024 (j), block (32 b, 8 ky); K=512 -> 64 per ky
__global__ __launch_bounds__(256) void k_x1(
    const float* __restrict__ preA_t, const float* __restrict__ z,
    const uint8_t* __restrict__ reset_t,
    const float* __restrict__ Wz, float* __restrict__ x1)
{
    int j = blockIdx.x;
    int b = threadIdx.x, y = threadIdx.y;
    const float* zp = z  + (size_t)b * STOCH + y * 64;
    const float* wp = Wz + (size_t)j * STOCH + y * 64;
    float ax = 0.f, ay = 0.f, az = 0.f, aw = 0.f;
#pragma unroll
    for (int k = 0; k < 64; k += 4) {
        float4 zv = *reinterpret_cast<const float4*>(zp + k);
        float4 wv = *reinterpret_cast<const float4*>(wp + k);
        ax += zv.x * wv.x; ay += zv.y * wv.y; az += zv.z * wv.z; aw += zv.w * wv.w;
    }
    __shared__ float red[8][33];
    red[y][b] = (ax + ay) + (az + aw);
    __syncthreads();
    if (y == 0) {
        float s = 0.f;
#pragma unroll
        for (int i = 0; i < 8; i++) s += red[i][b];
        float m = reset_t[b] ? 0.f : 1.f;
        x1[(size_t)b * HIDDEN + j] = preA_t[(size_t)b * HIDDEN + j] + m * s;
    }
}

// ---------------- in-place LN + elu over rows of length HIDDEN
// grid = #rows, block 256 (each thread one float4). Safe in-place per row.
__global__ __launch_bounds__(256) void k_ln_elu(
    float* __restrict__ X, const float* __restrict__ g, const float* __restrict__ bb)
{
    __shared__ float sbuf[256];
    __shared__ float qbuf[256];
    int r = blockIdx.x, t = threadIdx.x;
    float* row = X + (size_t)r * HIDDEN;
    float4 v = reinterpret_cast<const float4*>(row)[t];
    sbuf[t] = (v.x + v.y) + (v.z + v.w);
    qbuf[t] = (v.x * v.x + v.y * v.y) + (v.z * v.z + v.w * v.w);
    __syncthreads();
    for (int off = 128; off > 0; off >>= 1) {
        if (t < off) { sbuf[t] += sbuf[t + off]; qbuf[t] += qbuf[t + off]; }
        __syncthreads();
    }
    float mean = sbuf[0] / HIDDEN;
    float var = qbuf[0] / HIDDEN - mean * mean;
    float rstd = rsqrtf(var + 1e-5f);
    float4 gg = reinterpret_cast<const float4*>(g)[t];
    float4 bv = reinterpret_cast<const float4*>(bb)[t];
    float4 o;
    o.x = eluf((v.x - mean) * rstd * gg.x + bv.x);
    o.y = eluf((v.y - mean) * rstd * gg.y + bv.y);
    o.z = eluf((v.z - mean) * rstd * gg.z + bv.z);
    o.w = eluf((v.w - mean) * rstd * gg.w + bv.w);
    reinterpret_cast<float4*>(row)[t] = o;
}

// ---------------- GRU: grid 2048 (j), block (32 b, 8 ky)
// gi over za (K=1024, 128/ky), gh over h (K=2048, 256/ky), gates, h_new
__global__ __launch_bounds__(256) void k_gru(
    const float* __restrict__ za,
    const float* __restrict__ Wih, const float* __restrict__ Whh,
    const float* __restrict__ bih, const float* __restrict__ bhh,
    const float* __restrict__ hprev, int hstride,
    const uint8_t* __restrict__ reset_t,
    float* __restrict__ hout /* stride FEAT */)
{
    int j = blockIdx.x;
    int b = threadIdx.x, y = threadIdx.y;
    float girs, gius, gins;
    {
        const float* zp = za + (size_t)b * HIDDEN + y * 128;
        const float* wr = Wih + (size_t)j * HIDDEN + y * 128;
        const float* wu = wr + (size_t)DETER * HIDDEN;
        const float* wn = wu + (size_t)DETER * HIDDEN;
        float4 ar = {0,0,0,0}, au = {0,0,0,0}, an = {0,0,0,0};
#pragma unroll 4
        for (int k = 0; k < 128; k += 4) {
            float4 zv = *reinterpret_cast<const float4*>(zp + k);
            float4 a = *reinterpret_cast<const float4*>(wr + k);
            float4 c = *reinterpret_cast<const float4*>(wu + k);
            float4 d = *reinterpret_cast<const float4*>(wn + k);
            ar.x += zv.x * a.x; ar.y += zv.y * a.y; ar.z += zv.z * a.z; ar.w += zv.w * a.w;
            au.x += zv.x * c.x; au.y += zv.y * c.y; au.z += zv.z * c.z; au.w += zv.w * c.w;
            an.x += zv.x * d.x; an.y += zv.y * d.y; an.z += zv.z * d.z; an.w += zv.w * d.w;
        }
        girs = (ar.x + ar.y) + (ar.z + ar.w);
        gius = (au.x + au.y) + (au.z + au.w);
        gins = (an.x + an.y) + (an.z + an.w);
    }
    const float* hp = hprev + (size_t)b * hstride;
    float hrs, hus, hns;
    {
        const float* hq = hp + y * 256;
        const float* vr = Whh + (size_t)j * DETER + y * 256;
        const float* vu = vr + (size_t)DETER * DETER;
        const float* vn = vu + (size_t)DETER * DETER;
        float4 ar = {0,0,0,0}, au = {0,0,0,0}, an = {0,0,0,0};
#pragma unroll 4
        for (int k = 0; k < 256; k += 4) {
            float4 hv = *reinterpret_cast<const float4*>(hq + k);
            float4 a = *reinterpret_cast<const float4*>(vr + k);
            float4 c = *reinterpret_cast<const float4*>(vu + k);
            float4 d = *reinterpret_cast<const float4*>(vn + k);
            ar.x += hv.x * a.x; ar.y += hv.y * a.y; ar.z += hv.z * a.z; ar.w += hv.w * a.w;
            au.x += hv.x * c.x; au.y += hv.y * c.y; au.z += hv.z * c.z; au.w += hv.w * c.w;
            an.x += hv.x * d.x; an.y += hv.y * d.y; an.z += hv.z * d.z; an.w += hv.w * d.w;
        }
        hrs = (ar.x + ar.y) + (ar.z + ar.w);
        hus = (au.x + au.y) + (au.z + au.w);
        hns = (an.x + an.y) + (an.z + an.w);
    }
    __shared__ float red[8][32][6];
    red[y][b][0] = girs; red[y][b][1] = gius; red[y][b][2] = gins;
    red[y][b][3] = hrs;  red[y][b][4] = hus;  red[y][b][5] = hns;
    __syncthreads();
    if (y == 0) {
        float g0 = 0, g1 = 0, g2 = 0, h0 = 0, h1 = 0, h2 = 0;
#pragma unroll
        for (int i = 0; i < 8; i++) {
            g0 += red[i][b][0]; g1 += red[i][b][1]; g2 += red[i][b][2];
            h0 += red[i][b][3]; h1 += red[i][b][4]; h2 += red[i][b][5];
        }
        float m = reset_t[b] ? 0.f : 1.f;
        float gi_r = bih[j] + g0, gi_u = bih[j + DETER] + g1, gi_n = bih[j + 2 * DETER] + g2;
        float gh_r = bhh[j] + m * h0, gh_u = bhh[j + DETER] + m * h1, gh_n = bhh[j + 2 * DETER] + m * h2;
        float r = sigf(gi_r + gh_r);
        float u = sigf(gi_u + gh_u);
        float cand = tanhf(gi_n + r * gh_n);
        hout[(size_t)b * FEAT + j] = (1.f - u) * cand + u * (m * hp[j]);
    }
}

// ---------------- x2[b][j] = preE_t[b][j] + sum_k h[b][k] Wph[j][k]
// grid 1024 (j), block (32 b, 8 ky); K=2048 -> 256 per ky
__global__ __launch_bounds__(256) void k_x2(
    const float* __restrict__ preE_t, const float* __restrict__ h /*stride FEAT*/,
    const float* __restrict__ Wph, float* __restrict__ x2)
{
    int j = blockIdx.x;
    int b = threadIdx.x, y = threadIdx.y;
    const float* hq = h + (size_t)b * FEAT + y * 256;
    const float* wp = Wph + (size_t)j * DETER + y * 256;
    float4 a4 = {0,0,0,0};
#pragma unroll 4
    for (int k = 0; k < 256; k += 4) {
        float4 hv = *reinterpret_cast<const float4*>(hq + k);
        float4 wv = *reinterpret_cast<const float4*>(wp + k);
        a4.x += hv.x * wv.x; a4.y += hv.y * wv.y; a4.z += hv.z * wv.z; a4.w += hv.w * wv.w;
    }
    __shared__ float red[8][33];
    red[y][b] = (a4.x + a4.y) + (a4.z + a4.w);
    __syncthreads();
    if (y == 0) {
        float s = 0.f;
#pragma unroll
        for (int i = 0; i < 8; i++) s += red[i][b];
        x2[(size_t)b * HIDDEN + j] = preE_t[(size_t)b * HIDDEN + j] + s;
    }
}

// ---------------- post: grid 512 (j), block (32 b, 8 ky); pin already LN+elu'd
__global__ __launch_bounds__(256) void k_post(
    const float* __restrict__ pin,
    const float* __restrict__ Wpost, const float* __restrict__ bpost,
    const float* __restrict__ noise_t,
    float* __restrict__ posts_t,
    float* __restrict__ samples_t,
    float* __restrict__ feat_t)
{
    int j = blockIdx.x;
    int b = threadIdx.x, y = threadIdx.y;
    const float* pp = pin + (size_t)b * HIDDEN + y * 128;
    const float* wm = Wpost + (size_t)j * HIDDEN + y * 128;
    const float* wsp = Wpost + (size_t)(j + STOCH) * HIDDEN + y * 128;
    float4 am = {0,0,0,0}, as = {0,0,0,0};
#pragma unroll 4
    for (int k = 0; k < 128; k += 4) {
        float4 pv = *reinterpret_cast<const float4*>(pp + k);
        float4 a = *reinterpret_cast<const float4*>(wm + k);
        float4 c = *reinterpret_cast<const float4*>(wsp + k);
        am.x += pv.x * a.x; am.y += pv.y * a.y; am.z += pv.z * a.z; am.w += pv.w * a.w;
        as.x += pv.x * c.x; as.y += pv.y * c.y; as.z += pv.z * c.z; as.w += pv.w * c.w;
    }
    __shared__ float red[8][32][2];
    red[y][b][0] = (am.x + am.y) + (am.z + am.w);
    red[y][b][1] = (as.x + as.y) + (as.z + as.w);
    __syncthreads();
    if (y == 0) {
        float pm = bpost[j], ps = bpost[j + STOCH];
#pragma unroll
        for (int i = 0; i < 8; i++) { pm += red[i][b][0]; ps += red[i][b][1]; }
        posts_t[(size_t)b * HIDDEN + j] = pm;
        posts_t[(size_t)b * HIDDEN + STOCH + j] = ps;
        float sp = fmaxf(ps, 0.f) + log1pf(expf(-fabsf(ps)));
        float stdv = sp + 0.1f;
        float smp = pm + stdv * noise_t[(size_t)b * STOCH + j];
        samples_t[(size_t)b * STOCH + j] = smp;
        feat_t[(size_t)b * FEAT + DETER + j] = smp;
    }
}

__global__ __launch_bounds__(256) void k_copy_last(
    const float* __restrict__ feat63, const float* __restrict__ samp63,
    float* __restrict__ hlast, float* __restrict__ zlast)
{
    int i = blockIdx.x * 256 + threadIdx.x;
    if (i < BATCH * DETER) {
        int b = i / DETER, k = i % DETER;
        hlast[i] = feat63[(size_t)b * FEAT + k];
    }
    if (i < BATCH * STOCH) {
        zlast[i] = samp63[i];
    }
}

extern "C" void kernel_launch(void* const* d_in, const int* in_sizes, int n_in,
                              void* d_out, int out_size, void* d_ws, size_t ws_size,
                              hipStream_t stream)
{
    (void)in_sizes; (void)n_in; (void)out_size; (void)ws_size;
    const float*   embed  = (const float*)d_in[0];
    const float*   action = (const float*)d_in[1];
    const uint8_t* reset  = (const uint8_t*)d_in[2];
    const float*   h0     = (const float*)d_in[3];
    const float*   z0     = (const float*)d_in[4];
    const float*   noises = (const float*)d_in[5];
    const float*   W_z    = (const float*)d_in[6];
    const float*   b_z    = (const float*)d_in[7];
    const float*   W_a    = (const float*)d_in[8];
    const float*   ln_in_g = (const float*)d_in[9];
    const float*   ln_in_b = (const float*)d_in[10];
    const float*   Wih    = (const float*)d_in[11];
    const float*   Whh    = (const float*)d_in[12];
    const float*   bih    = (const float*)d_in[13];
    const float*   bhh    = (const float*)d_in[14];
    const float*   W_ph   = (const float*)d_in[15];
    const float*   b_ph   = (const float*)d_in[16];
    const float*   W_pe   = (const float*)d_in[17];
    const float*   ln_post_g = (const float*)d_in[18];
    const float*   ln_post_b = (const float*)d_in[19];
    const float*   W_post = (const float*)d_in[20];
    const float*   b_post = (const float*)d_in[21];
    const float*   W_prh  = (const float*)d_in[22];
    const float*   b_prh  = (const float*)d_in[23];
    const float*   ln_pr_g = (const float*)d_in[24];
    const float*   ln_pr_b = (const float*)d_in[25];
    const float*   W_pr   = (const float*)d_in[26];
    const float*   b_pr   = (const float*)d_in[27];

    float* out     = (float*)d_out;
    float* priors  = out;                  // 64*32*1024
    float* posts   = out + 2097152;        // 64*32*1024
    float* samples = out + 4194304;        // 64*32*512
    float* feats   = out + 5242880;        // 64*32*2560
    float* hlast   = out + 10485760;       // 32*2048
    float* zlast   = out + 10551296;       // 32*512

    float* ws   = (float*)d_ws;
    float* preA = ws;                // 2097152 floats
    float* preE = ws + 2097152;      // 2097152 floats
    float* x1   = ws + 4194304;      // 32768 (becomes za in-place)
    float* x2   = ws + 4227072;      // 32768 (becomes pin in-place)
    float* prx  = preA;              // alias: preA dead after the scan

    dim3 blk256(256);
    dim3 b32x8(32, 8);
    const int RB = (NSTEP * BATCH) / 64;   // 32 row-blocks of 64

    // precompute: preA = b_z + action @ W_a^T ; preE = b_ph + embed @ W_pe^T
    gemm_bt_bias<<<dim3(HIDDEN / 64, RB), blk256, 0, stream>>>(action, ACT_D, W_a, ACT_D, b_z, preA, HIDDEN, ACT_D);
    gemm_bt_bias<<<dim3(HIDDEN / 64, RB), blk256, 0, stream>>>(embed, EMBED_D, W_pe, EMBED_D, b_ph, preE, HIDDEN, EMBED_D);

    for (int t = 0; t < NSTEP; ++t) {
        const float* z = (t == 0) ? z0 : (samples + (size_t)(t - 1) * BATCH * STOCH);
        const float* h = (t == 0) ? h0 : (feats + (size_t)(t - 1) * BATCH * FEAT);
        int hstride = (t == 0) ? DETER : FEAT;
        const uint8_t* rs = reset + (size_t)t * BATCH;
        float* h_t = feats + (size_t)t * BATCH * FEAT;

        k_x1<<<dim3(HIDDEN), b32x8, 0, stream>>>(preA + (size_t)t * BATCH * HIDDEN, z, rs, W_z, x1);
        k_ln_elu<<<dim3(BATCH), blk256, 0, stream>>>(x1, ln_in_g, ln_in_b);
        k_gru<<<dim3(DETER), b32x8, 0, stream>>>(x1, Wih, Whh, bih, bhh, h, hstride, rs, h_t);
        k_x2<<<dim3(HIDDEN), b32x8, 0, stream>>>(preE + (size_t)t * BATCH * HIDDEN, h_t, W_ph, x2);
        k_ln_elu<<<dim3(BATCH), blk256, 0, stream>>>(x2, ln_post_g, ln_post_b);
        k_post<<<dim3(STOCH), b32x8, 0, stream>>>(x2, W_post, b_post,
            noises + (size_t)t * BATCH * STOCH,
            posts + (size_t)t * BATCH * HIDDEN,
            samples + (size_t)t * BATCH * STOCH,
            h_t);
    }

    // prior over all states_h (rows of feats, first DETER cols)
    gemm_bt_bias<<<dim3(HIDDEN / 64, RB), blk256, 0, stream>>>(feats, FEAT, W_prh, DETER, b_prh, prx, HIDDEN, DETER);
    k_ln_elu<<<dim3(NSTEP * BATCH), blk256, 0, stream>>>(prx, ln_pr_g, ln_pr_b);
    gemm_bt_bias<<<dim3(HIDDEN / 64, RB), blk256, 0, stream>>>(prx, HIDDEN, W_pr, HIDDEN, b_pr, priors, HIDDEN, HIDDEN);

    k_copy_last<<<dim3(256), blk256, 0, stream>>>(
        feats + (size_t)(NSTEP - 1) * BATCH * FEAT,
        samples + (size_t)(NSTEP - 1) * BATCH * STOCH,
        hlast, zlast);
}

// Round 3
// 6824.590 us; speedup vs baseline: 2.7173x; 2.1412x over previous
//
#include <hip/hip_runtime.h>
#include <hip/hip_bf16.h>
#include <stdint.h>

#define NSTEP 64
#define BATCH 32
#define EMBED_D 1536
#define ACT_D 16
#define DETER 2048
#define STOCH 512
#define HIDDEN 1024
#define FEAT 2560

typedef __attribute__((ext_vector_type(8))) short bf16x8;
typedef __attribute__((ext_vector_type(4))) float f32x4;

__device__ __forceinline__ float eluf(float x) { return x > 0.f ? x : expf(x) - 1.f; }
__device__ __forceinline__ float sigf(float x) { return 1.f / (1.f + expf(-x)); }
__device__ __forceinline__ unsigned short f2bf(float f) {
    __hip_bfloat16 h = __float2bfloat16(f);
    return __builtin_bit_cast(unsigned short, h);
}

// ---------- f32 -> bf16 bulk convert (n multiple of 1024)
__global__ __launch_bounds__(256) void k_cvt(const float* __restrict__ src,
                                             unsigned short* __restrict__ dst, int n)
{
    int i = (blockIdx.x * 256 + threadIdx.x) * 4;
    if (i < n) {
        float4 v = *reinterpret_cast<const float4*>(src + i);
        ushort4 o;
        o.x = f2bf(v.x); o.y = f2bf(v.y); o.z = f2bf(v.z); o.w = f2bf(v.w);
        *reinterpret_cast<ushort4*>(dst + i) = o;
    }
}

// ---------- fused x1 = b_z + act@Wa^T + m*(z@Wz^T); LN+elu; -> za16 (bf16)
// grid 32 (b), 256 thr
__global__ __launch_bounds__(256) void k_x1ln(
    const float* __restrict__ z, const float* __restrict__ act_t,
    const uint8_t* __restrict__ reset_t,
    const float* __restrict__ Wz, const float* __restrict__ Wa,
    const float* __restrict__ bz,
    const float* __restrict__ g, const float* __restrict__ bb,
    unsigned short* __restrict__ za16)
{
    __shared__ float zl[512];
    __shared__ float al[16];
    __shared__ float sbuf[256], qbuf[256];
    int b = blockIdx.x, t = threadIdx.x;
    if (t < 128) *reinterpret_cast<float4*>(&zl[t * 4]) =
        *reinterpret_cast<const float4*>(&z[(size_t)b * STOCH + t * 4]);
    if (t < 16) al[t] = act_t[b * ACT_D + t];
    __syncthreads();
    float m = reset_t[b] ? 0.f : 1.f;
    float vj[4]; float s = 0.f, q = 0.f;
#pragma unroll
    for (int i = 0; i < 4; i++) {
        int j = i * 256 + t;
        const float* wr = Wz + (size_t)j * STOCH;
        float4 a4 = {0, 0, 0, 0};
        for (int k = 0; k < STOCH; k += 4) {
            float4 wv = *reinterpret_cast<const float4*>(wr + k);
            float4 zv = *reinterpret_cast<const float4*>(&zl[k]);
            a4.x += zv.x * wv.x; a4.y += zv.y * wv.y;
            a4.z += zv.z * wv.z; a4.w += zv.w * wv.w;
        }
        float da = 0.f;
        const float* war = Wa + j * ACT_D;
#pragma unroll
        for (int k = 0; k < ACT_D; k++) da += al[k] * war[k];
        float v = bz[j] + da + m * ((a4.x + a4.y) + (a4.z + a4.w));
        vj[i] = v; s += v; q += v * v;
    }
    sbuf[t] = s; qbuf[t] = q; __syncthreads();
    for (int off = 128; off > 0; off >>= 1) {
        if (t < off) { sbuf[t] += sbuf[t + off]; qbuf[t] += qbuf[t + off]; }
        __syncthreads();
    }
    float mean = sbuf[0] / HIDDEN;
    float var = qbuf[0] / HIDDEN - mean * mean;
    float rstd = rsqrtf(var + 1e-5f);
#pragma unroll
    for (int i = 0; i < 4; i++) {
        int j = i * 256 + t;
        za16[(size_t)b * HIDDEN + j] = f2bf(eluf((vj[i] - mean) * rstd * g[j] + bb[j]));
    }
}

// ---------- gates MFMA: Gi = za@Wih^T ; Gh0/Gh1 = h@Whh^T (K halves)
// grid 288 (96 gi + 96 gh0 + 96 gh1), 256 thr (4 waves), K=1024 per block
__global__ __launch_bounds__(256) void k_gates(
    const unsigned short* __restrict__ za16, const unsigned short* __restrict__ h16,
    const unsigned short* __restrict__ Wih16, const unsigned short* __restrict__ Whh16,
    float* __restrict__ Gi, float* __restrict__ Gh0, float* __restrict__ Gh1)
{
    __shared__ unsigned short Alds[32 * 1032];
    int bid = blockIdx.x, t = threadIdx.x;
    const unsigned short* A; int srcld, koff; const unsigned short* W; int ldw;
    float* out; int nb;
    if (bid < 96)       { A = za16; srcld = 1024; koff = 0;    W = Wih16; ldw = 1024; out = Gi;  nb = bid; }
    else if (bid < 192) { A = h16;  srcld = 2048; koff = 0;    W = Whh16; ldw = 2048; out = Gh0; nb = bid - 96; }
    else                { A = h16;  srcld = 2048; koff = 1024; W = Whh16; ldw = 2048; out = Gh1; nb = bid - 192; }
    {
        int row = t >> 3, sub = t & 7;
        const unsigned short* src = A + (size_t)row * srcld + koff + sub * 128;
        unsigned short* dst = &Alds[row * 1032 + sub * 128];
#pragma unroll
        for (int i = 0; i < 16; i++)
            *reinterpret_cast<uint4*>(dst + i * 8) = *reinterpret_cast<const uint4*>(src + i * 8);
    }
    __syncthreads();
    int w = t >> 6, l = t & 63, l15 = l & 15, kg = l >> 4;
    int n = nb * 64 + w * 16 + l15;
    const unsigned short* Wrow = W + (size_t)n * ldw + koff + kg * 8;
    const unsigned short* a0p = &Alds[l15 * 1032 + kg * 8];
    const unsigned short* a1p = a0p + 16 * 1032;
    f32x4 acc0 = {0, 0, 0, 0}, acc1 = {0, 0, 0, 0};
#pragma unroll 4
    for (int s = 0; s < 32; s++) {
        bf16x8 bf = *reinterpret_cast<const bf16x8*>(Wrow + s * 32);
        bf16x8 a0 = *reinterpret_cast<const bf16x8*>(a0p + s * 32);
        bf16x8 a1 = *reinterpret_cast<const bf16x8*>(a1p + s * 32);
        acc0 = __builtin_amdgcn_mfma_f32_16x16x32_bf16(a0, bf, acc0, 0, 0, 0);
        acc1 = __builtin_amdgcn_mfma_f32_16x16x32_bf16(a1, bf, acc1, 0, 0, 0);
    }
#pragma unroll
    for (int i = 0; i < 4; i++) {
        out[(size_t)(kg * 4 + i) * 6144 + n] = acc0[i];
        out[(size_t)(kg * 4 + i + 16) * 6144 + n] = acc1[i];
    }
}

// ---------- GRU combine: gates + h_new; writes feats (f32) and h16 (bf16)
// grid 64, 256 thr
__global__ __launch_bounds__(256) void k_comb(
    const float* __restrict__ Gi, const float* __restrict__ Gh0, const float* __restrict__ Gh1,
    const float* __restrict__ bih, const float* __restrict__ bhh,
    const float* __restrict__ hprev, int hstride, const uint8_t* __restrict__ reset_t,
    float* __restrict__ feats_t, unsigned short* __restrict__ h16)
{
    int t = threadIdx.x;
    int j = blockIdx.x * 32 + (t & 31);
    int b0 = t >> 5;
    for (int b = b0; b < 32; b += 8) {
        float m = reset_t[b] ? 0.f : 1.f;
        size_t o = (size_t)b * 6144 + j;
        float gr = Gi[o]        + bih[j];
        float gu = Gi[o + 2048] + bih[j + 2048];
        float gn = Gi[o + 4096] + bih[j + 4096];
        float hr = m * (Gh0[o]        + Gh1[o])        + bhh[j];
        float hu = m * (Gh0[o + 2048] + Gh1[o + 2048]) + bhh[j + 2048];
        float hn = m * (Gh0[o + 4096] + Gh1[o + 4096]) + bhh[j + 4096];
        float r = sigf(gr + hr);
        float u = sigf(gu + hu);
        float cand = tanhf(gn + r * hn);
        float hnew = (1.f - u) * cand + u * (m * hprev[(size_t)b * hstride + j]);
        feats_t[(size_t)b * FEAT + j] = hnew;
        h16[b * DETER + j] = f2bf(hnew);
    }
}

// ---------- x2 partial MFMA: x2p[c] = h16 @ Wph^T (K half c)
// grid 32 (16 nb x 2 halves), 256 thr
__global__ __launch_bounds__(256) void k_x2(
    const unsigned short* __restrict__ h16, const unsigned short* __restrict__ Wph16,
    float* __restrict__ x2p)
{
    __shared__ unsigned short Alds[32 * 1032];
    int bid = blockIdx.x, t = threadIdx.x;
    int c = bid >> 4, nb = bid & 15;
    int koff = c * 1024;
    {
        int row = t >> 3, sub = t & 7;
        const unsigned short* src = h16 + (size_t)row * 2048 + koff + sub * 128;
        unsigned short* dst = &Alds[row * 1032 + sub * 128];
#pragma unroll
        for (int i = 0; i < 16; i++)
            *reinterpret_cast<uint4*>(dst + i * 8) = *reinterpret_cast<const uint4*>(src + i * 8);
    }
    __syncthreads();
    int w = t >> 6, l = t & 63, l15 = l & 15, kg = l >> 4;
    int n = nb * 64 + w * 16 + l15;
    const unsigned short* Wrow = Wph16 + (size_t)n * 2048 + koff + kg * 8;
    const unsigned short* a0p = &Alds[l15 * 1032 + kg * 8];
    const unsigned short* a1p = a0p + 16 * 1032;
    f32x4 acc0 = {0, 0, 0, 0}, acc1 = {0, 0, 0, 0};
#pragma unroll 4
    for (int s = 0; s < 32; s++) {
        bf16x8 bf = *reinterpret_cast<const bf16x8*>(Wrow + s * 32);
        bf16x8 a0 = *reinterpret_cast<const bf16x8*>(a0p + s * 32);
        bf16x8 a1 = *reinterpret_cast<const bf16x8*>(a1p + s * 32);
        acc0 = __builtin_amdgcn_mfma_f32_16x16x32_bf16(a0, bf, acc0, 0, 0, 0);
        acc1 = __builtin_amdgcn_mfma_f32_16x16x32_bf16(a1, bf, acc1, 0, 0, 0);
    }
    float* outp = x2p + (size_t)c * 32768;
#pragma unroll
    for (int i = 0; i < 4; i++) {
        outp[(size_t)(kg * 4 + i) * 1024 + n] = acc0[i];
        outp[(size_t)(kg * 4 + i + 16) * 1024 + n] = acc1[i];
    }
}

// ---------- LN(preE_t + x2p0 + x2p1) + elu -> pin16 (bf16); grid 32
__global__ __launch_bounds__(256) void k_lncvt2(
    const float* __restrict__ preE_t, const float* __restrict__ x2p,
    const float* __restrict__ g, const float* __restrict__ bb,
    unsigned short* __restrict__ pin16)
{
    __shared__ float sbuf[256], qbuf[256];
    int b = blockIdx.x, t = threadIdx.x;
    size_t o = (size_t)b * 1024 + t * 4;
    float4 v  = *reinterpret_cast<const float4*>(&preE_t[o]);
    float4 p0 = *reinterpret_cast<const float4*>(&x2p[o]);
    float4 p1 = *reinterpret_cast<const float4*>(&x2p[32768 + o]);
    v.x += p0.x + p1.x; v.y += p0.y + p1.y; v.z += p0.z + p1.z; v.w += p0.w + p1.w;
    sbuf[t] = (v.x + v.y) + (v.z + v.w);
    qbuf[t] = (v.x * v.x + v.y * v.y) + (v.z * v.z + v.w * v.w);
    __syncthreads();
    for (int off = 128; off > 0; off >>= 1) {
        if (t < off) { sbuf[t] += sbuf[t + off]; qbuf[t] += qbuf[t + off]; }
        __syncthreads();
    }
    float mean = sbuf[0] / HIDDEN;
    float var = qbuf[0] / HIDDEN - mean * mean;
    float rstd = rsqrtf(var + 1e-5f);
    float4 gg = reinterpret_cast<const float4*>(g)[t];
    float4 bv = reinterpret_cast<const float4*>(bb)[t];
    ushort4 ov;
    ov.x = f2bf(eluf((v.x - mean) * rstd * gg.x + bv.x));
    ov.y = f2bf(eluf((v.y - mean) * rstd * gg.y + bv.y));
    ov.z = f2bf(eluf((v.z - mean) * rstd * gg.z + bv.z));
    ov.w = f2bf(eluf((v.w - mean) * rstd * gg.w + bv.w));
    *reinterpret_cast<ushort4*>(&pin16[o]) = ov;
}

// ---------- post MFMA + sample: grid 16 (j-tiles of 32), 256 thr
__global__ __launch_bounds__(256) void k_post_sample(
    const unsigned short* __restrict__ pin16, const unsigned short* __restrict__ Wpo16,
    const float* __restrict__ bpost, const float* __restrict__ noise_t,
    float* __restrict__ posts_t, float* __restrict__ samples_t, float* __restrict__ feat_t)
{
    __shared__ unsigned short Alds[32 * 1032];
    __shared__ float buf[32 * 64];
    int jb = blockIdx.x, t = threadIdx.x;
    {
        int row = t >> 3, sub = t & 7;
        const unsigned short* src = pin16 + (size_t)row * 1024 + sub * 128;
        unsigned short* dst = &Alds[row * 1032 + sub * 128];
#pragma unroll
        for (int i = 0; i < 16; i++)
            *reinterpret_cast<uint4*>(dst + i * 8) = *reinterpret_cast<const uint4*>(src + i * 8);
    }
    __syncthreads();
    int w = t >> 6, l = t & 63, l15 = l & 15, kg = l >> 4;
    int n = (w < 2) ? (jb * 32 + w * 16 + l15) : (512 + jb * 32 + (w - 2) * 16 + l15);
    const unsigned short* Wrow = Wpo16 + (size_t)n * 1024 + kg * 8;
    const unsigned short* a0p = &Alds[l15 * 1032 + kg * 8];
    const unsigned short* a1p = a0p + 16 * 1032;
    f32x4 acc0 = {0, 0, 0, 0}, acc1 = {0, 0, 0, 0};
#pragma unroll 4
    for (int s = 0; s < 32; s++) {
        bf16x8 bf = *reinterpret_cast<const bf16x8*>(Wrow + s * 32);
        bf16x8 a0 = *reinterpret_cast<const bf16x8*>(a0p + s * 32);
        bf16x8 a1 = *reinterpret_cast<const bf16x8*>(a1p + s * 32);
        acc0 = __builtin_amdgcn_mfma_f32_16x16x32_bf16(a0, bf, acc0, 0, 0, 0);
        acc1 = __builtin_amdgcn_mfma_f32_16x16x32_bf16(a1, bf, acc1, 0, 0, 0);
    }
    float bias = bpost[n];
    int lc = w * 16 + l15;
#pragma unroll
    for (int i = 0; i < 4; i++) {
        buf[(kg * 4 + i) * 64 + lc] = acc0[i] + bias;
        buf[(kg * 4 + i + 16) * 64 + lc] = acc1[i] + bias;
    }
    __syncthreads();
#pragma unroll
    for (int it = 0; it < 4; it++) {
        int b = (t >> 5) + it * 8;
        int jl = t & 31;
        int j = jb * 32 + jl;
        float mean = buf[b * 64 + jl];
        float sraw = buf[b * 64 + 32 + jl];
        posts_t[(size_t)b * 1024 + j] = mean;
        posts_t[(size_t)b * 1024 + 512 + j] = sraw;
        float sp = fmaxf(sraw, 0.f) + log1pf(expf(-fabsf(sraw)));
        float smp = mean + (sp + 0.1f) * noise_t[(size_t)b * 512 + j];
        samples_t[(size_t)b * 512 + j] = smp;
        feat_t[(size_t)b * FEAT + DETER + j] = smp;
    }
}

// ---------- one-shot MFMA GEMM, f32 sources converted while staging
// C[r][n] = bias[n] + sum_k A[r][k]*B[n][k]; grid (N/64, M/64), 256 thr
__global__ __launch_bounds__(256) void gemm_mfma(
    const float* __restrict__ A, int lda,
    const float* __restrict__ B, int ldb,
    const float* __restrict__ bias,
    float* __restrict__ C, int ldc, int K)
{
    __shared__ unsigned short Alds[64 * 72];
    __shared__ unsigned short Blds[64 * 72];
    int t = threadIdx.x;
    int nb = blockIdx.x, mb = blockIdx.y;
    int w = t >> 6, l = t & 63, l15 = l & 15, kg = l >> 4;
    f32x4 acc[4] = {{0,0,0,0},{0,0,0,0},{0,0,0,0},{0,0,0,0}};
    int srow = t >> 2, skq = (t & 3) * 16;
    const float* Asrc = A + (size_t)(mb * 64 + srow) * lda + skq;
    const float* Bsrc = B + (size_t)(nb * 64 + srow) * ldb + skq;
    unsigned short* Adst = &Alds[srow * 72 + skq];
    unsigned short* Bdst = &Blds[srow * 72 + skq];
    for (int kt = 0; kt < K; kt += 64) {
        __syncthreads();
#pragma unroll
        for (int c = 0; c < 16; c += 4) {
            float4 va = *reinterpret_cast<const float4*>(Asrc + kt + c);
            float4 vb = *reinterpret_cast<const float4*>(Bsrc + kt + c);
            ushort4 oa, ob;
            oa.x = f2bf(va.x); oa.y = f2bf(va.y); oa.z = f2bf(va.z); oa.w = f2bf(va.w);
            ob.x = f2bf(vb.x); ob.y = f2bf(vb.y); ob.z = f2bf(vb.z); ob.w = f2bf(vb.w);
            *reinterpret_cast<ushort4*>(Adst + c) = oa;
            *reinterpret_cast<ushort4*>(Bdst + c) = ob;
        }
        __syncthreads();
#pragma unroll
        for (int ks = 0; ks < 2; ks++) {
            bf16x8 a = *reinterpret_cast<const bf16x8*>(&Alds[(w * 16 + l15) * 72 + ks * 32 + kg * 8]);
#pragma unroll
            for (int nt = 0; nt < 4; nt++) {
                bf16x8 b = *reinterpret_cast<const bf16x8*>(&Blds[(nt * 16 + l15) * 72 + ks * 32 + kg * 8]);
                acc[nt] = __builtin_amdgcn_mfma_f32_16x16x32_bf16(a, b, acc[nt], 0, 0, 0);
            }
        }
    }
#pragma unroll
    for (int nt = 0; nt < 4; nt++) {
        int n = nb * 64 + nt * 16 + l15;
        float bv = bias[n];
#pragma unroll
        for (int i = 0; i < 4; i++) {
            C[(size_t)(mb * 64 + w * 16 + kg * 4 + i) * ldc + n] = acc[nt][i] + bv;
        }
    }
}

// ---------- row LN+elu in place (f32), rows of 1024; grid = #rows
__global__ __launch_bounds__(256) void ln_elu_rows(
    float* __restrict__ X, const float* __restrict__ g, const float* __restrict__ bb)
{
    __shared__ float sbuf[256], qbuf[256];
    int r = blockIdx.x, t = threadIdx.x;
    float* row = X + (size_t)r * HIDDEN;
    float4 v = reinterpret_cast<const float4*>(row)[t];
    sbuf[t] = (v.x + v.y) + (v.z + v.w);
    qbuf[t] = (v.x * v.x + v.y * v.y) + (v.z * v.z + v.w * v.w);
    __syncthreads();
    for (int off = 128; off > 0; off >>= 1) {
        if (t < off) { sbuf[t] += sbuf[t + off]; qbuf[t] += qbuf[t + off]; }
        __syncthreads();
    }
    float mean = sbuf[0] / HIDDEN;
    float var = qbuf[0] / HIDDEN - mean * mean;
    float rstd = rsqrtf(var + 1e-5f);
    float4 gg = reinterpret_cast<const float4*>(g)[t];
    float4 bv = reinterpret_cast<const float4*>(bb)[t];
    float4 o;
    o.x = eluf((v.x - mean) * rstd * gg.x + bv.x);
    o.y = eluf((v.y - mean) * rstd * gg.y + bv.y);
    o.z = eluf((v.z - mean) * rstd * gg.z + bv.z);
    o.w = eluf((v.w - mean) * rstd * gg.w + bv.w);
    reinterpret_cast<float4*>(row)[t] = o;
}

__global__ __launch_bounds__(256) void k_copy_last(
    const float* __restrict__ feat63, const float* __restrict__ samp63,
    float* __restrict__ hlast, float* __restrict__ zlast)
{
    int i = blockIdx.x * 256 + threadIdx.x;
    if (i < BATCH * DETER) {
        int b = i / DETER, k = i % DETER;
        hlast[i] = feat63[(size_t)b * FEAT + k];
    }
    if (i < BATCH * STOCH) zlast[i] = samp63[i];
}

// ws byte offsets
#define WS_WZ16   ((size_t)0)
#define WS_WIH16  ((size_t)1048576)
#define WS_WHH16  ((size_t)13631488)
#define WS_WPH16  ((size_t)38797312)
#define WS_WPO16  ((size_t)42991616)
#define WS_ZA16   ((size_t)45088768)
#define WS_H16    (WS_ZA16 + 65536)
#define WS_PIN16  (WS_H16 + 131072)
#define WS_GI     (WS_PIN16 + 65536)
#define WS_GH0    (WS_GI + 786432)
#define WS_GH1    (WS_GH0 + 786432)
#define WS_X2P    (WS_GH1 + 786432)
#define WS_PRX    WS_WIH16   // alias: Wih16 dead after scan

extern "C" void kernel_launch(void* const* d_in, const int* in_sizes, int n_in,
                              void* d_out, int out_size, void* d_ws, size_t ws_size,
                              hipStream_t stream)
{
    (void)in_sizes; (void)n_in; (void)out_size; (void)ws_size;
    const float*   embed  = (const float*)d_in[0];
    const float*   action = (const float*)d_in[1];
    const uint8_t* reset  = (const uint8_t*)d_in[2];
    const float*   h0     = (const float*)d_in[3];
    const float*   z0     = (const float*)d_in[4];
    const float*   noises = (const float*)d_in[5];
    const float*   W_z    = (const float*)d_in[6];
    const float*   b_z    = (const float*)d_in[7];
    const float*   W_a    = (const float*)d_in[8];
    const float*   ln_in_g = (const float*)d_in[9];
    const float*   ln_in_b = (const float*)d_in[10];
    const float*   Wih    = (const float*)d_in[11];
    const float*   Whh    = (const float*)d_in[12];
    const float*   bih    = (const float*)d_in[13];
    const float*   bhh    = (const float*)d_in[14];
    const float*   W_ph   = (const float*)d_in[15];
    const float*   b_ph   = (const float*)d_in[16];
    const float*   W_pe   = (const float*)d_in[17];
    const float*   ln_post_g = (const float*)d_in[18];
    const float*   ln_post_b = (const float*)d_in[19];
    const float*   W_post = (const float*)d_in[20];
    const float*   b_post = (const float*)d_in[21];
    const float*   W_prh  = (const float*)d_in[22];
    const float*   b_prh  = (const float*)d_in[23];
    const float*   ln_pr_g = (const float*)d_in[24];
    const float*   ln_pr_b = (const float*)d_in[25];
    const float*   W_pr   = (const float*)d_in[26];
    const float*   b_pr   = (const float*)d_in[27];

    float* out     = (float*)d_out;
    float* priors  = out;                  // also preE scratch during scan
    float* posts   = out + 2097152;
    float* samples = out + 4194304;
    float* feats   = out + 5242880;
    float* hlast   = out + 10485760;
    float* zlast   = out + 10551296;

    char* ws = (char*)d_ws;
    unsigned short* Wz16  = (unsigned short*)(ws + WS_WZ16);
    unsigned short* Wih16 = (unsigned short*)(ws + WS_WIH16);
    unsigned short* Whh16 = (unsigned short*)(ws + WS_WHH16);
    unsigned short* Wph16 = (unsigned short*)(ws + WS_WPH16);
    unsigned short* Wpo16 = (unsigned short*)(ws + WS_WPO16);
    unsigned short* za16  = (unsigned short*)(ws + WS_ZA16);
    unsigned short* h16   = (unsigned short*)(ws + WS_H16);
    unsigned short* pin16 = (unsigned short*)(ws + WS_PIN16);
    float* Gi  = (float*)(ws + WS_GI);
    float* Gh0 = (float*)(ws + WS_GH0);
    float* Gh1 = (float*)(ws + WS_GH1);
    float* x2p = (float*)(ws + WS_X2P);
    float* prx = (float*)(ws + WS_PRX);

    dim3 blk(256);

    // weight conversions (note: Wz16 unused by kernels; x1 uses f32 Wz directly)
    k_cvt<<<dim3(512),   blk, 0, stream>>>(W_z,    Wz16,  524288);
    k_cvt<<<dim3(6144),  blk, 0, stream>>>(Wih,    Wih16, 6291456);
    k_cvt<<<dim3(12288), blk, 0, stream>>>(Whh,    Whh16, 12582912);
    k_cvt<<<dim3(2048),  blk, 0, stream>>>(W_ph,   Wph16, 2097152);
    k_cvt<<<dim3(1024),  blk, 0, stream>>>(W_post, Wpo16, 1048576);
    k_cvt<<<dim3(64),    blk, 0, stream>>>(h0,     h16,   65536);

    // preE = b_ph + embed @ W_pe^T   (into priors region; dead until the end)
    gemm_mfma<<<dim3(16, 32), blk, 0, stream>>>(embed, EMBED_D, W_pe, EMBED_D, b_ph,
                                                priors, HIDDEN, EMBED_D);

    for (int t = 0; t < NSTEP; ++t) {
        const float* z = (t == 0) ? z0 : (samples + (size_t)(t - 1) * BATCH * STOCH);
        const float* hprev = (t == 0) ? h0 : (feats + (size_t)(t - 1) * BATCH * FEAT);
        int hstride = (t == 0) ? DETER : FEAT;
        const uint8_t* rs = reset + (size_t)t * BATCH;
        float* feats_t = feats + (size_t)t * BATCH * FEAT;
        const float* preE_t = priors + (size_t)t * BATCH * HIDDEN;

        k_x1ln<<<dim3(32), blk, 0, stream>>>(z, action + (size_t)t * BATCH * ACT_D, rs,
                                             W_z, W_a, b_z, ln_in_g, ln_in_b, za16);
        k_gates<<<dim3(288), blk, 0, stream>>>(za16, h16, Wih16, Whh16, Gi, Gh0, Gh1);
        k_comb<<<dim3(64), blk, 0, stream>>>(Gi, Gh0, Gh1, bih, bhh, hprev, hstride, rs,
                                             feats_t, h16);
        k_x2<<<dim3(32), blk, 0, stream>>>(h16, Wph16, x2p);
        k_lncvt2<<<dim3(32), blk, 0, stream>>>(preE_t, x2p, ln_post_g, ln_post_b, pin16);
        k_post_sample<<<dim3(16), blk, 0, stream>>>(pin16, Wpo16, b_post,
            noises + (size_t)t * BATCH * STOCH,
            posts + (size_t)t * BATCH * HIDDEN,
            samples + (size_t)t * BATCH * STOCH,
            feats_t);
    }

    // prior chain
    gemm_mfma<<<dim3(16, 32), blk, 0, stream>>>(feats, FEAT, W_prh, DETER, b_prh,
                                                prx, HIDDEN, DETER);
    ln_elu_rows<<<dim3(2048), blk, 0, stream>>>(prx, ln_pr_g, ln_pr_b);
    gemm_mfma<<<dim3(16, 32), blk, 0, stream>>>(prx, HIDDEN, W_pr, HIDDEN, b_pr,
                                                priors, HIDDEN, HIDDEN);

    k_copy_last<<<dim3(256), blk, 0, stream>>>(
        feats + (size_t)(NSTEP - 1) * BATCH * FEAT,
        samples + (size_t)(NSTEP - 1) * BATCH * STOCH,
        hlast, zlast);
}